// Round 1
// baseline (309.444 us; speedup 1.0000x reference)
//
#include <hip/hip_runtime.h>
#include <math.h>

// Pool2d: 3x3 max pool, stride 2, pad 1 (fill 0.0), dilation 1.
// X: (32,192,224,224) f32 NCHW -> Y: (32,192,112,112) f32.
// Memory-bound: 1.233 GB in + 0.308 GB out => ~245 us floor @ 6.3 TB/s.

namespace {
constexpr int H = 224;
constexpr int W = 224;
constexpr int HO = 112;
constexpr int WO = 112;
constexpr int QPR = WO / 4;                 // 28 float4-quads per output row
constexpr int NROWS = 32 * 192 * HO;        // 688,128 output rows (n*c*oy)
constexpr int TOTAL_QUADS = NROWS * QPR;    // 19,267,584
}

__global__ __launch_bounds__(256) void pool3x3s2_kernel(
    const float* __restrict__ X, float* __restrict__ Y) {
  const int stride = gridDim.x * blockDim.x;
  for (int idx = blockIdx.x * blockDim.x + threadIdx.x; idx < TOTAL_QUADS;
       idx += stride) {
    const int q   = idx % QPR;        // quad within output row (magic-mul div)
    const int row = idx / QPR;        // global output row = nc*HO + oy
    const int oy  = row % HO;
    const int nc  = row / HO;

    const float* __restrict__ img = X + (size_t)nc * (H * W);
    const int iy0 = 2 * oy - 1;       // top of 3-row window (may be -1)
    const int ixs = 8 * q;            // leftmost aligned input x; scalar at ixs-1

    float m0 = -INFINITY, m1 = -INFINITY, m2 = -INFINITY, m3 = -INFINITY;

#pragma unroll
    for (int dy = 0; dy < 3; ++dy) {
      const int iy = iy0 + dy;
      float a, b0, b1, b2, b3, b4, b5, b6, b7;
      if (0 <= iy && iy < H) {
        const float* __restrict__ r = img + iy * W;
        // left tap: pad(0.0) only when q==0 (ix = -1)
        a = (ixs > 0) ? r[ixs - 1] : 0.0f;
        const float4 v0 = *reinterpret_cast<const float4*>(r + ixs);      // 16B aligned
        const float4 v1 = *reinterpret_cast<const float4*>(r + ixs + 4);  // 16B aligned
        b0 = v0.x; b1 = v0.y; b2 = v0.z; b3 = v0.w;
        b4 = v1.x; b5 = v1.y; b6 = v1.z; b7 = v1.w;
      } else {
        // entire row is padding -> contributes fill value 0.0 to the max
        a = b0 = b1 = b2 = b3 = b4 = b5 = b6 = b7 = 0.0f;
      }
      // output j taps input x = 2j-1, 2j, 2j+1 (relative to ixs-1 .. ixs+7)
      m0 = fmaxf(m0, fmaxf(a,  fmaxf(b0, b1)));
      m1 = fmaxf(m1, fmaxf(b1, fmaxf(b2, b3)));
      m2 = fmaxf(m2, fmaxf(b3, fmaxf(b4, b5)));
      m3 = fmaxf(m3, fmaxf(b5, fmaxf(b6, b7)));
    }

    float4 o;
    o.x = m0; o.y = m1; o.z = m2; o.w = m3;
    *reinterpret_cast<float4*>(Y + (size_t)row * WO + 4 * q) = o;  // 16B aligned
  }
}

extern "C" void kernel_launch(void* const* d_in, const int* in_sizes, int n_in,
                              void* d_out, int out_size, void* d_ws, size_t ws_size,
                              hipStream_t stream) {
  const float* X = (const float*)d_in[0];
  float* Y = (float*)d_out;
  // Memory-bound: cap grid and grid-stride (G11). 2048 blocks x 256 thr,
  // ~37 quads per thread.
  pool3x3s2_kernel<<<2048, 256, 0, stream>>>(X, Y);
}